// Round 12
// baseline (30958.359 us; speedup 1.0000x reference)
//
#include <hip/hip_runtime.h>
#include <math.h>

#define NBLK 512
#define NTHR 256

typedef float f32x4 __attribute__((ext_vector_type(4)));

// -------- coherent (cross-XCD) 16B asm access; rule-18 discipline: ldr4 after vm0 --------
__device__ __forceinline__ f32x4 ld4c(const float* p){
    f32x4 v;
    asm volatile("global_load_dwordx4 %0, %1, off sc0 sc1" : "=v"(v) : "v"(p) : "memory");
    return v;
}
__device__ __forceinline__ void st4c(float* p, f32x4 v){
    asm volatile("global_store_dwordx4 %0, %1, off sc0 sc1" :: "v"(p), "v"(v) : "memory");
}
__device__ __forceinline__ void vm0(){ asm volatile("s_waitcnt vmcnt(0)" ::: "memory"); }
__device__ __forceinline__ f32x4 ldr4(f32x4 v){ asm volatile("" : "+v"(v)); return v; }

// -------- small coherent atomics (proven R5/R7) --------
__device__ __forceinline__ float2 ld2a(const float* p){
    unsigned long long u = __hip_atomic_load((const unsigned long long*)p,
                                             __ATOMIC_RELAXED, __HIP_MEMORY_SCOPE_AGENT);
    float2 r;
    r.x = __uint_as_float((unsigned)u);
    r.y = __uint_as_float((unsigned)(u >> 32));
    return r;
}
__device__ __forceinline__ void st2a(float* p, float a, float b){
    unsigned long long u = (unsigned long long)__float_as_uint(a)
                         | ((unsigned long long)__float_as_uint(b) << 32);
    __hip_atomic_store((unsigned long long*)p, u,
                       __ATOMIC_RELAXED, __HIP_MEMORY_SCOPE_AGENT);
}
__device__ __forceinline__ float ld1a(const float* p){
    unsigned u = __hip_atomic_load((const unsigned*)p, __ATOMIC_RELAXED, __HIP_MEMORY_SCOPE_AGENT);
    return __uint_as_float(u);
}
__device__ __forceinline__ void st1a(float* p, float v){
    __hip_atomic_store((unsigned*)p, __float_as_uint(v), __ATOMIC_RELAXED, __HIP_MEMORY_SCOPE_AGENT);
}

__device__ __forceinline__ float fsigmoid(float x){ return 1.0f/(1.0f + __expf(-x)); }
__device__ __forceinline__ float ftanh(float x){
    float e = __expf(2.0f*x);          // inf-safe
    return 1.0f - 2.0f/(e + 1.0f);
}
__device__ __forceinline__ float dot4(f32x4 a, f32x4 b){
    return a.x*b.x + a.y*b.y + a.z*b.z + a.w*b.w;
}

struct Params {
    const float* input_p; const float* mask_p; const float* input_q; const float* mask_q;
    const float* W_ih; const float* W_hh; const float* bias;
    const float* ln_i_g; const float* ln_i_b; const float* ln_h_g; const float* ln_h_b;
    const float* ln_c_g; const float* ln_c_b;
    const float* Wq; const float* Wp; const float* Wr; const float* w_att; const float* b_att;
    float* out;
    float* qWq;    // [2][2048][768] read-only
    float* iqT;    // [16][768][128] read-only
    float* pWp0;   // [2048][768]
    float* pWih0;  // [2048][3072]
    // coherent buffers (h,c,sP0,whP0 contiguous for prologue zeroing)
    float* h;      // [2][16][768]
    float* c;      // [2][16][768]
    float* sP0;    // [8][16][768]   Wr0 x h0 copies
    float* whP0;   // [8][16][3072]  Whh0 x h0 copies
    float* sP1h;   // [8][16][768]   Wr1 x h1
    float* whP1;   // [8][16][3072]  Whh1 x h1
    float* sP1c;   // [8][16][768]   Wp1 x h0
    float* cwP1;   // [8][16][3072]  Wih1cur x h0
    float* wiP;    // [8][16][3072]  Wih_w x weighted
    float* whR0;   // [16][3072]
    float* whR1;   // [16][3072]
    float* cwR1;   // [16][3072]
    float* sR0;    // [16][768]
    float* sR1h;   // [16][768]
    float* wghtd0; // [16][768]
    float* wghtd1; // [16][768]
    float* escore; // [16][128]
    unsigned* bar;
};

// -------- monotonic tree barrier (512 blocks = 32 leaves x 16), proven R5/R7 --------
__device__ __forceinline__ void gsync(unsigned* bar, int bid, unsigned n){
    __syncthreads();
    if (threadIdx.x == 0){
        unsigned* leaf = bar + 128 + (bid >> 4)*32;
        unsigned old = __hip_atomic_fetch_add(leaf, 1u, __ATOMIC_RELAXED, __HIP_MEMORY_SCOPE_AGENT);
        if ((old & 15u) == 15u){
            unsigned rold = __hip_atomic_fetch_add(bar + 32, 1u, __ATOMIC_RELAXED, __HIP_MEMORY_SCOPE_AGENT);
            if ((rold & 31u) == 31u){
                __hip_atomic_store(bar, n + 1u, __ATOMIC_RELEASE, __HIP_MEMORY_SCOPE_AGENT);
            }
        }
        int spins = 0;
        while (__hip_atomic_load(bar, __ATOMIC_RELAXED, __HIP_MEMORY_SCOPE_AGENT) < n + 1u){
            __builtin_amdgcn_s_sleep(4);
            if (++spins > 1024){
                (void)__hip_atomic_load(bar, __ATOMIC_ACQUIRE, __HIP_MEMORY_SCOPE_AGENT);
                spins = 0;
            }
        }
    }
    __syncthreads();
}

__device__ __forceinline__ float bsum4(float v, float* red, int tid){
    #pragma unroll
    for (int off = 32; off; off >>= 1) v += __shfl_xor(v, off);
    __syncthreads();
    if ((tid & 63) == 0) red[tid >> 6] = v;
    __syncthreads();
    float s = red[0]+red[1]+red[2]+red[3];
    __syncthreads();
    return s;
}

__global__ __launch_bounds__(NTHR, 2) void coop_kernel(Params p)
{
    __shared__ float smem[6936];
    const int tid = threadIdx.x;
    const int bid = blockIdx.x;
    unsigned n = 0;

    // stage 16x96 f32 slice (rows stride 768) from coherent src into smem[16][96]
    auto stage96 = [&](const float* src, int k0){
        int r0 = tid/24, kk0 = (tid%24)*4;
        f32x4 v0 = ld4c(src + (size_t)r0*768 + k0 + kk0);
        f32x4 v1;
        int i1 = tid + 256, r1 = i1/24, kk1 = (i1%24)*4;
        if (tid < 128) v1 = ld4c(src + (size_t)r1*768 + k0 + kk1);
        vm0();
        v0 = ldr4(v0); *(f32x4*)&smem[r0*96 + kk0] = v0;
        if (tid < 128){ v1 = ldr4(v1); *(f32x4*)&smem[r1*96 + kk1] = v1; }
        __syncthreads();
    };

    // 128-col tile, K=96 partial. threads: cg=tid&31 (4 cols), rg=tid>>5 (rows rg, rg+8)
    auto mm96w = [&](const float* W, int N, float* outP, int cbase, int k0){
        int cg = tid & 31, rg = tid >> 5;
        int col = cbase + cg*4;
        const float* Wc = W + (size_t)k0*N + col;
        const float* A0 = smem + rg*96;
        const float* A1 = smem + (rg+8)*96;
        f32x4 acc0 = {0,0,0,0}, acc1 = {0,0,0,0};
        for (int kb = 0; kb < 96; kb += 8){
            f32x4 w[8];
            #pragma unroll
            for (int j = 0; j < 8; j++)
                w[j] = *(const f32x4*)(Wc + (size_t)(kb+j)*N);
            #pragma unroll
            for (int j = 0; j < 8; j++){
                acc0 += A0[kb+j]*w[j];
                acc1 += A1[kb+j]*w[j];
            }
        }
        float* o = outP + (size_t)rg*N + col;
        st4c(o, acc0);
        st4c(o + (size_t)8*N, acc1);
        __syncthreads();
    };

    // S2a scores: 256 blocks (bid 256..511), 16 per batch, 8 scores each.
    auto s2a = [&](int d, const float* sR, const float* sPc, float* esc){
        int bb = (bid - 256) >> 4, sq0 = ((bid - 256) & 15)*8;
        float* s_sh  = smem;
        float* wa_sh = smem + 768;
        if (tid < 192){
            f32x4 acc;
            f32x4 v0 = ld4c(sR + bb*768 + tid*4);
            f32x4 vc[8];
            if (sPc){
                #pragma unroll
                for (int cp = 0; cp < 8; cp++)
                    vc[cp] = ld4c(sPc + (size_t)cp*12288 + bb*768 + tid*4);
            }
            vm0();
            acc = ldr4(v0);
            if (sPc){
                #pragma unroll
                for (int cp = 0; cp < 8; cp++){ vc[cp] = ldr4(vc[cp]); acc += vc[cp]; }
            }
            *(f32x4*)&s_sh[tid*4] = acc;
        } else {
            int i0 = tid - 192;
            for (int rr = 0; rr < 3; rr++){
                int i = i0 + rr*64;
                *(f32x4*)&wa_sh[i*4] = *(const f32x4*)(p.w_att + d*768 + i*4);
            }
        }
        __syncthreads();
        int sq = sq0 + (tid >> 5), l = tid & 31;
        const float* qrow = p.qWq + ((size_t)(d*2048 + bb*128 + sq))*768;
        float part = 0.f;
        #pragma unroll
        for (int i = 0; i < 6; i++){
            int a = i*128 + l*4;
            f32x4 q  = *(const f32x4*)(qrow + a);
            f32x4 s4 = *(const f32x4*)(s_sh + a);
            f32x4 w4 = *(const f32x4*)(wa_sh + a);
            part += ftanh(q.x + s4.x)*w4.x + ftanh(q.y + s4.y)*w4.y
                  + ftanh(q.z + s4.z)*w4.z + ftanh(q.w + s4.w)*w4.w;
        }
        #pragma unroll
        for (int off = 16; off; off >>= 1) part += __shfl_xor(part, off, 32);
        if (l == 0){
            float e = (p.mask_q[bb*128 + sq] > 0.f) ? __expf(part) : 0.f;
            st1a(esc + bb*128 + sq, e);
        }
        __syncthreads();
    };

    // S2b weighted: 64 blocks (bid<64), 4 per batch, 192 cols each
    auto s2b = [&](float* wout){
        int bb = bid >> 2, cg = bid & 3;
        float* e_sh = smem;    // 129
        if (tid < 128) e_sh[tid] = ld1a(p.escore + bb*128 + tid);
        __syncthreads();
        if (tid < 64){
            float v = e_sh[tid] + e_sh[tid + 64];
            #pragma unroll
            for (int off = 32; off; off >>= 1) v += __shfl_xor(v, off);
            if (tid == 0) e_sh[128] = 1.0f / v;
        }
        __syncthreads();
        float inv = e_sh[128];
        if (tid < 192){
            int cc = cg*192 + tid;
            const float* ip = p.iqT + ((size_t)bb*768 + cc)*128;
            float acc = 0.f;
            #pragma unroll 8
            for (int j = 0; j < 32; j++){
                f32x4 q  = *(const f32x4*)(ip + j*4);
                f32x4 e4 = *(const f32x4*)&e_sh[j*4];
                acc += dot4(q, e4);
            }
            st1a(wout + bb*768 + cc, acc*inv);
        }
        __syncthreads();
    };

    // reduce 8 copies of [16][3072] -> dst ; 48 blocks starting at boff
    auto red8big = [&](const float* src, float* dst, int boff){
        int gid = (bid - boff)*NTHR + tid;   // < 12288 f4
        f32x4 v[8];
        #pragma unroll
        for (int cp = 0; cp < 8; cp++)
            v[cp] = ld4c(src + (size_t)cp*49152 + gid*4);
        vm0();
        f32x4 a = {0,0,0,0};
        #pragma unroll
        for (int cp = 0; cp < 8; cp++){ v[cp] = ldr4(v[cp]); a += v[cp]; }
        st4c(dst + gid*4, a);
    };

    // reduce 8 copies of [16][768] + b_att(+pWp0) -> sR ; 16 blocks starting at boff
    auto redS = [&](const float* srcP, float* dst, int d, const float* pw, int tt, int boff){
        int bb = bid - boff;
        if (tid < 192){
            f32x4 v[8];
            #pragma unroll
            for (int cp = 0; cp < 8; cp++)
                v[cp] = ld4c(srcP + (size_t)cp*12288 + bb*768 + tid*4);
            vm0();
            f32x4 a = *(const f32x4*)(p.b_att + d*768 + tid*4);
            if (pw) a += *(const f32x4*)(pw + ((size_t)bb*128 + tt)*768 + tid*4);
            #pragma unroll
            for (int cp = 0; cp < 8; cp++){ v[cp] = ldr4(v[cp]); a += v[cp]; }
            st4c(dst + bb*768 + tid*4, a);
        }
    };

    // gates: 16 blocks (bid<16)
    auto gates = [&](int d, int t){
        int bb = bid;
        float* wi_sh = smem;
        float* wh_sh = smem + 3072;
        float* c_sh  = smem + 6144;
        float* red   = smem + 6928;
        const float mmv = p.mask_p[bb*128 + t];
        const float* gi = p.ln_i_g + d*3072; const float* bi = p.ln_i_b + d*3072;
        const float* gh = p.ln_h_g + d*3072; const float* bh = p.ln_h_b + d*3072;
        const float* gc = p.ln_c_g + d*768;  const float* bc = p.ln_c_b + d*768;
        const float* bias_d = p.bias + d*3072;
        const float* whR = d ? p.whR1 : p.whR0;

        float swi=0,qwi=0,swh=0,qwh=0;
        #pragma unroll
        for (int rep = 0; rep < 3; rep++){
            int j4 = tid + rep*256;
            int base = bb*3072 + j4*4;
            f32x4 v[8], wv, cv;
            #pragma unroll
            for (int cp = 0; cp < 8; cp++)
                v[cp] = ld4c(p.wiP + (size_t)cp*49152 + base);
            wv = ld4c(whR + base);
            if (d == 1) cv = ld4c(p.cwR1 + base);
            vm0();
            f32x4 a = {0,0,0,0};
            #pragma unroll
            for (int cp = 0; cp < 8; cp++){ v[cp] = ldr4(v[cp]); a += v[cp]; }
            if (d == 0){
                a += *(const f32x4*)(p.pWih0 + ((size_t)bb*128 + t)*3072 + j4*4);
            } else {
                cv = ldr4(cv); a += cv;
            }
            wv = ldr4(wv);
            *(f32x4*)&wi_sh[j4*4] = a;
            *(f32x4*)&wh_sh[j4*4] = wv;
            swi += a.x+a.y+a.z+a.w;   qwi += dot4(a,a);
            swh += wv.x+wv.y+wv.z+wv.w; qwh += dot4(wv,wv);
        }
        swi = bsum4(swi, red, tid);
        qwi = bsum4(qwi, red, tid);
        swh = bsum4(swh, red, tid);
        qwh = bsum4(qwh, red, tid);
        float mi = swi/3072.f, vi = fmaxf((qwi - 3072.f*mi*mi)/3071.f, 0.f);
        float mh = swh/3072.f, vh = fmaxf((qwh - 3072.f*mh*mh)/3071.f, 0.f);
        float ivi = 1.f/(sqrtf(vi + 1e-6f) + 1e-6f);
        float ivh = 1.f/(sqrtf(vh + 1e-6f) + 1e-6f);

        for (int j = tid; j < 3072; j += NTHR){
            float pre = mmv*(gi[j]*(wi_sh[j]-mi)*ivi + bi[j])
                      + mmv*(gh[j]*(wh_sh[j]-mh)*ivh + bh[j])
                      + bias_d[j];
            wi_sh[j] = pre;
        }
        __syncthreads();

        float sc=0,qc=0;
        for (int idx = tid; idx < 384; idx += NTHR){
            int u = idx*2;
            float2 c_old = ld2a(p.c + (size_t)d*12288 + bb*768 + u);
            float f0  = wi_sh[u],        f1  = wi_sh[u+1];
            float i0  = wi_sh[768+u],    i1  = wi_sh[768+u+1];
            float g0  = wi_sh[2304+u],   g1  = wi_sh[2304+u+1];
            float c10 = fsigmoid(f0)*c_old.x + fsigmoid(i0)*ftanh(g0);
            float c11 = fsigmoid(f1)*c_old.y + fsigmoid(i1)*ftanh(g1);
            c10 = c10*mmv + c_old.x*(1.f - mmv);
            c11 = c11*mmv + c_old.y*(1.f - mmv);
            st2a(p.c + (size_t)d*12288 + bb*768 + u, c10, c11);
            c_sh[u] = c10; c_sh[u+1] = c11;
            sc += c10 + c11; qc += c10*c10 + c11*c11;
        }
        sc = bsum4(sc, red, tid);
        qc = bsum4(qc, red, tid);
        float mc = sc/768.f, vc = fmaxf((qc - 768.f*mc*mc)/767.f, 0.f);
        float ivc = 1.f/(sqrtf(vc + 1e-6f) + 1e-6f);

        for (int idx = tid; idx < 384; idx += NTHR){
            int u = idx*2;
            float2 h_old = ld2a(p.h + (size_t)d*12288 + bb*768 + u);
            float o0 = wi_sh[1536+u], o1 = wi_sh[1536+u+1];
            float l0 = (gc[u]*(c_sh[u]-mc)*ivc + bc[u])*mmv;
            float l1 = (gc[u+1]*(c_sh[u+1]-mc)*ivc + bc[u+1])*mmv;
            float h10 = fsigmoid(o0)*ftanh(l0);
            float h11 = fsigmoid(o1)*ftanh(l1);
            h10 = h10*mmv + h_old.x*(1.f - mmv);
            h11 = h11*mmv + h_old.y*(1.f - mmv);
            st2a(p.h + (size_t)d*12288 + bb*768 + u, h10, h11);
            if (d == 1){
                float2 ov = { h10, h11 };
                *(float2*)(p.out + ((size_t)bb*128 + t)*768 + u) = ov;
            }
        }
        __syncthreads();
    };

    // ---- prologue: zero h,c,sP0,whP0 (contiguous 540672 f32); write mask tail ----
    {
        int gid = bid*NTHR + tid;
        f32x4 z = {0,0,0,0};
        for (int i4 = gid; i4 < 135168; i4 += NBLK*NTHR)
            st4c(p.h + (size_t)i4*4, z);
        if (gid < 2048) p.out[(size_t)16*128*768 + gid] = p.mask_p[gid];
    }
    gsync(p.bar, bid, n); n++;

    // ---- pre-loop: sR0(t=0) and whR0(=0) from zeroed copies ----
    if (bid >= 16 && bid < 64)      red8big(p.whP0, p.whR0, 16);
    else if (bid >= 64 && bid < 80) redS(p.sP0, p.sR0, 0, p.pWp0, 0, 64);
    gsync(p.bar, bid, n); n++;

    for (int t = 0; t < 128; ++t){
        // ===== A: [Wr1,Whh1] x h1(t-1) (240 blocks)  ||  S2a d=0 (256 blocks) =====
        if (bid < 240){
            int tile = bid >> 3, kc = bid & 7, k0 = kc*96;
            stage96(p.h + 12288, k0);
            if (tile < 6)
                mm96w(p.Wr + (size_t)589824, 768, p.sP1h + (size_t)kc*12288, tile*128, k0);
            else
                mm96w(p.W_hh + (size_t)2359296, 3072, p.whP1 + (size_t)kc*49152, (tile-6)*128, k0);
        } else if (bid >= 256){
            s2a(0, p.sR0, nullptr, p.escore);
        }
        gsync(p.bar, bid, n); n++;

        // ===== B: S2b d=0 (64)  ||  whP1 -> whR1 (48) =====
        if (bid < 64)                    s2b(p.wghtd0);
        else if (bid >= 64 && bid < 112) red8big(p.whP1, p.whR1, 64);
        gsync(p.bar, bid, n); n++;

        // ===== C: S3 d=0: wi = weighted0 @ Wih0_w (192 blocks) =====
        if (bid < 192){
            int tile = bid >> 3, kc = bid & 7, k0 = kc*96;
            stage96(p.wghtd0, k0);
            mm96w(p.W_ih + (size_t)2359296, 3072, p.wiP + (size_t)kc*49152, tile*128, k0);
        }
        gsync(p.bar, bid, n); n++;

        // ===== D: gates d=0 -> h0(t), c0(t) (16 blocks) =====
        if (bid < 16) gates(0, t);
        gsync(p.bar, bid, n); n++;

        // ===== E: [Wp1,Wih1cur] x h0(t) (240)  ||  sP1h -> sR1h (16) =====
        if (bid < 240){
            int tile = bid >> 3, kc = bid & 7, k0 = kc*96;
            stage96(p.h, k0);
            if (tile < 6)
                mm96w(p.Wp + (size_t)589824, 768, p.sP1c + (size_t)kc*12288, tile*128, k0);
            else
                mm96w(p.W_ih + (size_t)4718592, 3072, p.cwP1 + (size_t)kc*49152, (tile-6)*128, k0);
        } else if (bid >= 240 && bid < 256){
            redS(p.sP1h, p.sR1h, 1, nullptr, 0, 240);
        }
        gsync(p.bar, bid, n); n++;

        // ===== F: [Wr0,Whh0] x h0(t) for t+1 (240)  ||  S2a d=1 (256) =====
        if (bid < 240){
            int tile = bid >> 3, kc = bid & 7, k0 = kc*96;
            stage96(p.h, k0);
            if (tile < 6)
                mm96w(p.Wr, 768, p.sP0 + (size_t)kc*12288, tile*128, k0);
            else
                mm96w(p.W_hh, 3072, p.whP0 + (size_t)kc*49152, (tile-6)*128, k0);
        } else if (bid >= 256){
            s2a(1, p.sR1h, p.sP1c, p.escore);
        }
        gsync(p.bar, bid, n); n++;

        // ===== G: S2b d=1 (64)  ||  cwP1 -> cwR1 (48) =====
        if (bid < 64)                    s2b(p.wghtd1);
        else if (bid >= 64 && bid < 112) red8big(p.cwP1, p.cwR1, 64);
        gsync(p.bar, bid, n); n++;

        // ===== H: S3 d=1 (192) =====
        if (bid < 192){
            int tile = bid >> 3, kc = bid & 7, k0 = kc*96;
            stage96(p.wghtd1, k0);
            mm96w(p.W_ih + (size_t)4718592 + (size_t)2359296, 3072,
                  p.wiP + (size_t)kc*49152, tile*128, k0);
        }
        gsync(p.bar, bid, n); n++;

        // ===== I: gates d=1 (16)  ||  whP0 -> whR0 (48)  ||  sP0 -> sR0[t+1] (16) =====
        if (bid < 16){
            gates(1, t);
        } else if (bid >= 16 && bid < 64){
            red8big(p.whP0, p.whR0, 16);
        } else if (bid >= 64 && bid < 80){
            int tt = (t + 1 < 128) ? t + 1 : 127;
            redS(p.sP0, p.sR0, 0, p.pWp0, tt, 64);
        }
        gsync(p.bar, bid, n); n++;
    }
}

// ---------- precompute GEMM (f32 out; validated R0/R5/R7 kernel) ----------
__global__ __launch_bounds__(256) void k_mm_pre(
    const float* __restrict__ Ain, const float* __restrict__ W,
    float* __restrict__ C, int ldw, int ncols)
{
    __shared__ float Ash[16][772];
    int rowbase = blockIdx.y*16;
    for (int r = 0; r < 16; r++)
        for (int i = threadIdx.x; i < 768; i += 256)
            Ash[r][i] = Ain[(size_t)(rowbase + r)*768 + i];
    __syncthreads();
    int lane = threadIdx.x & 63;
    int colq = lane & 15, rsub = lane >> 4, wq = threadIdx.x >> 6;
    int r = wq*4 + rsub;
    int col = blockIdx.x*64 + colq*4;
    float4 acc = {0.f,0.f,0.f,0.f};
    const float* Wc = W + col;
    for (int k = 0; k < 768; k += 4){
        float4 a4 = *(const float4*)&Ash[r][k];
        float4 w0 = *(const float4*)(Wc + (size_t)(k+0)*ldw);
        float4 w1 = *(const float4*)(Wc + (size_t)(k+1)*ldw);
        float4 w2 = *(const float4*)(Wc + (size_t)(k+2)*ldw);
        float4 w3 = *(const float4*)(Wc + (size_t)(k+3)*ldw);
        acc.x += a4.x*w0.x + a4.y*w1.x + a4.z*w2.x + a4.w*w3.x;
        acc.y += a4.x*w0.y + a4.y*w1.y + a4.z*w2.y + a4.w*w3.y;
        acc.z += a4.x*w0.z + a4.y*w1.z + a4.z*w2.z + a4.w*w3.z;
        acc.w += a4.x*w0.w + a4.y*w1.w + a4.z*w2.w + a4.w*w3.w;
    }
    *(float4*)(C + (size_t)(rowbase + r)*ncols + col) = acc;
}

// ---------- transpose input_q -> iqT[b][c][sq] f32 ----------
__global__ __launch_bounds__(256) void k_transq(
    const float* __restrict__ iq, float* __restrict__ iqT)
{
    __shared__ float Tsh[32][136];
    int c0 = blockIdx.x*32, b = blockIdx.y;
    for (int rep = 0; rep < 4; rep++){
        int idx = threadIdx.x + rep*256;
        int sq = idx >> 3, cq = idx & 7;
        float4 v = *(const float4*)(iq + ((size_t)b*128 + sq)*768 + c0 + cq*4);
        Tsh[cq*4+0][sq] = v.x;
        Tsh[cq*4+1][sq] = v.y;
        Tsh[cq*4+2][sq] = v.z;
        Tsh[cq*4+3][sq] = v.w;
    }
    __syncthreads();
    for (int rep = 0; rep < 4; rep++){
        int idx = threadIdx.x + rep*256;
        int cl = idx >> 5, sq4 = (idx & 31)*4;
        float4 v = *(const float4*)&Tsh[cl][sq4];
        *(float4*)(iqT + ((size_t)b*768 + c0 + cl)*128 + sq4) = v;
    }
}

extern "C" void kernel_launch(void* const* d_in, const int* in_sizes, int n_in,
                              void* d_out, int out_size, void* d_ws, size_t ws_size,
                              hipStream_t stream)
{
    (void)in_sizes; (void)n_in; (void)out_size; (void)ws_size;
    Params P;
    P.input_p = (const float*)d_in[0];
    P.mask_p  = (const float*)d_in[1];
    P.input_q = (const float*)d_in[2];
    P.mask_q  = (const float*)d_in[3];
    P.W_ih    = (const float*)d_in[4];
    P.W_hh    = (const float*)d_in[5];
    P.bias    = (const float*)d_in[6];
    P.ln_i_g  = (const float*)d_in[7];
    P.ln_i_b  = (const float*)d_in[8];
    P.ln_h_g  = (const float*)d_in[9];
    P.ln_h_b  = (const float*)d_in[10];
    P.ln_c_g  = (const float*)d_in[11];
    P.ln_c_b  = (const float*)d_in[12];
    P.Wq      = (const float*)d_in[13];
    P.Wp      = (const float*)d_in[14];
    P.Wr      = (const float*)d_in[15];
    P.w_att   = (const float*)d_in[16];
    P.b_att   = (const float*)d_in[17];
    P.out     = (float*)d_out;

    float* ws = (float*)d_ws;
    size_t off = 0;
    auto alloc = [&](size_t nfloat)->float*{
        float* r = ws + off;
        off += (nfloat + 63) & ~(size_t)63;
        return r;
    };
    P.qWq    = alloc((size_t)2*2048*768);
    P.iqT    = alloc((size_t)16*768*128);
    P.pWp0   = alloc((size_t)2048*768);
    P.pWih0  = alloc((size_t)2048*3072);
    // contiguous zero-range: h, c, sP0, whP0
    P.h      = alloc(24576);
    P.c      = alloc(24576);
    P.sP0    = alloc((size_t)8*12288);
    P.whP0   = alloc((size_t)8*49152);
    P.sP1h   = alloc((size_t)8*12288);
    P.whP1   = alloc((size_t)8*49152);
    P.sP1c   = alloc((size_t)8*12288);
    P.cwP1   = alloc((size_t)8*49152);
    P.wiP    = alloc((size_t)8*49152);
    P.whR0   = alloc(49152);
    P.whR1   = alloc(49152);
    P.cwR1   = alloc(49152);
    P.sR0    = alloc(12288);
    P.sR1h   = alloc(12288);
    P.wghtd0 = alloc(12288);
    P.wghtd1 = alloc(12288);
    P.escore = alloc(2048);
    P.bar    = (unsigned*)alloc(2048);

    (void)hipMemsetAsync((void*)P.bar, 0, 2048*sizeof(unsigned), stream);
    k_mm_pre<<<dim3(12,128), 256, 0, stream>>>(P.input_q, P.Wq, P.qWq, 768, 768);
    k_mm_pre<<<dim3(12,128), 256, 0, stream>>>(P.input_q, P.Wq + (size_t)589824,
                                               P.qWq + (size_t)2048*768, 768, 768);
    k_mm_pre<<<dim3(12,128), 256, 0, stream>>>(P.input_p, P.Wp, P.pWp0, 768, 768);
    k_mm_pre<<<dim3(48,128), 256, 0, stream>>>(P.input_p, P.W_ih, P.pWih0, 3072, 3072);
    k_transq<<<dim3(24,16), 256, 0, stream>>>(P.input_q, P.iqT);
    coop_kernel<<<dim3(NBLK), dim3(NTHR), 0, stream>>>(P);
}

// Round 14
// 17545.908 us; speedup vs baseline: 1.7644x; 1.7644x over previous
//
#include <hip/hip_runtime.h>
#include <math.h>

#define NBLK 768
#define NTHR 256

typedef float f32x4 __attribute__((ext_vector_type(4)));

// -------- coherent (cross-XCD) 16B asm access; rule-18 discipline: ldr4 after vm0,
// and ONLY in fully-unrolled constant-bound loops (rule #20: no scratch spills) --------
__device__ __forceinline__ f32x4 ld4c(const float* p){
    f32x4 v;
    asm volatile("global_load_dwordx4 %0, %1, off sc0 sc1" : "=v"(v) : "v"(p) : "memory");
    return v;
}
__device__ __forceinline__ void st4c(float* p, f32x4 v){
    asm volatile("global_store_dwordx4 %0, %1, off sc0 sc1" :: "v"(p), "v"(v) : "memory");
}
__device__ __forceinline__ void vm0(){ asm volatile("s_waitcnt vmcnt(0)" ::: "memory"); }
__device__ __forceinline__ f32x4 ldr4(f32x4 v){ asm volatile("" : "+v"(v)); return v; }

// non-temporal weight load: streaming data, do not pollute L2 (compiler-managed waits)
__device__ __forceinline__ f32x4 ldnt(const float* p){
    return __builtin_nontemporal_load((const f32x4*)p);
}

// -------- small coherent atomics (proven R5/R7) --------
__device__ __forceinline__ float2 ld2a(const float* p){
    unsigned long long u = __hip_atomic_load((const unsigned long long*)p,
                                             __ATOMIC_RELAXED, __HIP_MEMORY_SCOPE_AGENT);
    float2 r;
    r.x = __uint_as_float((unsigned)u);
    r.y = __uint_as_float((unsigned)(u >> 32));
    return r;
}
__device__ __forceinline__ void st2a(float* p, float a, float b){
    unsigned long long u = (unsigned long long)__float_as_uint(a)
                         | ((unsigned long long)__float_as_uint(b) << 32);
    __hip_atomic_store((unsigned long long*)p, u,
                       __ATOMIC_RELAXED, __HIP_MEMORY_SCOPE_AGENT);
}
__device__ __forceinline__ float ld1a(const float* p){
    unsigned u = __hip_atomic_load((const unsigned*)p, __ATOMIC_RELAXED, __HIP_MEMORY_SCOPE_AGENT);
    return __uint_as_float(u);
}
__device__ __forceinline__ void st1a(float* p, float v){
    __hip_atomic_store((unsigned*)p, __float_as_uint(v), __ATOMIC_RELAXED, __HIP_MEMORY_SCOPE_AGENT);
}

__device__ __forceinline__ float fsigmoid(float x){ return 1.0f/(1.0f + __expf(-x)); }
__device__ __forceinline__ float ftanh(float x){
    float e = __expf(2.0f*x);          // inf-safe
    return 1.0f - 2.0f/(e + 1.0f);
}
__device__ __forceinline__ float dot4(f32x4 a, f32x4 b){
    return a.x*b.x + a.y*b.y + a.z*b.z + a.w*b.w;
}

struct Params {
    const float* input_p; const float* mask_p; const float* input_q; const float* mask_q;
    const float* W_ih; const float* W_hh; const float* bias;
    const float* ln_i_g; const float* ln_i_b; const float* ln_h_g; const float* ln_h_b;
    const float* ln_c_g; const float* ln_c_b;
    const float* Wq; const float* Wp; const float* Wr; const float* w_att; const float* b_att;
    float* out;
    float* qWq;    // [2][2048][768] read-only
    float* iqT;    // [16][768][128] read-only
    float* pWp0;   // [2048][768]
    float* pWih0;  // [2048][3072]
    float* h;      // [2][16][768] coherent (c contiguous after)
    float* c;      // [2][16][768]
    float* sP;     // [12][16][768]  copies 0-5: Wr x h ; 6-11: Wp1 x h0 (d=1)
    float* whP;    // [6][16][3072]
    float* cwP;    // [6][16][3072]
    float* wiP;    // [6][16][3072]
    float* whR;    // [16][3072]
    float* cwR;    // [16][3072]
    float* wghtd;  // [16][768]
    float* escore; // [16][128]
    unsigned* bar;
};

// -------- monotonic tree barrier (768 blocks = 48 leaves x 16) --------
__device__ __forceinline__ void gsync(unsigned* bar, int bid, unsigned n){
    __syncthreads();
    if (threadIdx.x == 0){
        unsigned* leaf = bar + 128 + (bid >> 4)*32;
        unsigned old = __hip_atomic_fetch_add(leaf, 1u, __ATOMIC_RELAXED, __HIP_MEMORY_SCOPE_AGENT);
        if ((old & 15u) == 15u){
            unsigned rold = __hip_atomic_fetch_add(bar + 32, 1u, __ATOMIC_RELAXED, __HIP_MEMORY_SCOPE_AGENT);
            if ((rold % 48u) == 47u){
                __hip_atomic_store(bar, n + 1u, __ATOMIC_RELEASE, __HIP_MEMORY_SCOPE_AGENT);
            }
        }
        int spins = 0;
        while (__hip_atomic_load(bar, __ATOMIC_RELAXED, __HIP_MEMORY_SCOPE_AGENT) < n + 1u){
            __builtin_amdgcn_s_sleep(4);
            if (++spins > 1024){
                (void)__hip_atomic_load(bar, __ATOMIC_ACQUIRE, __HIP_MEMORY_SCOPE_AGENT);
                spins = 0;
            }
        }
    }
    __syncthreads();
}

__device__ __forceinline__ float bsum4(float v, float* red, int tid){
    #pragma unroll
    for (int off = 32; off; off >>= 1) v += __shfl_xor(v, off);
    __syncthreads();
    if ((tid & 63) == 0) red[tid >> 6] = v;
    __syncthreads();
    float s = red[0]+red[1]+red[2]+red[3];
    __syncthreads();
    return s;
}

__global__ __launch_bounds__(NTHR, 3) void coop_kernel(Params p)
{
    __shared__ float smem[6936];
    const int tid = threadIdx.x;
    const int bid = blockIdx.x;
    unsigned n = 0;

    // stage 16x128 f32 slice (row stride 768) from coherent src into smem[16][128]
    auto stage128 = [&](const float* src, int k0){
        #pragma unroll
        for (int rep = 0; rep < 2; rep++){
            int i4 = tid + rep*256;             // 512 f4 chunks, 32 per row
            int r = i4 >> 5, kk = (i4 & 31)*4;
            f32x4 v = ld4c(src + (size_t)r*768 + k0 + kk);
            vm0();
            v = ldr4(v);
            *(f32x4*)&smem[r*128 + kk] = v;
        }
        __syncthreads();
    };

    // 64-col tile, K=128 partial. thread: 1 row (rg=tid>>4) x 4 cols (cg=tid&15).
    // nt weight loads in 8-deep bursts; one 16B coherent store.
    auto mm128 = [&](const float* W, int N, float* outP, int cbase, int k0){
        int cg = tid & 15, rg = tid >> 4;
        int col = cbase + cg*4;
        const float* Wc = W + (size_t)k0*N + col;
        const float* Arow = smem + rg*128;
        f32x4 acc = {0,0,0,0};
        for (int kb = 0; kb < 128; kb += 8){
            f32x4 w[8];
            #pragma unroll
            for (int j = 0; j < 8; j++)
                w[j] = ldnt(Wc + (size_t)(kb+j)*N);
            #pragma unroll
            for (int j = 0; j < 8; j++)
                acc += Arow[kb+j]*w[j];
        }
        st4c(outP + (size_t)rg*N + col, acc);
        __syncthreads();
    };

    // S2a scores: 256 blocks, 16 per batch, 8 scores each.
    // Copy loops are FULLY STATIC per branch (R13 bug: runtime-bound asm-load loop
    // spilled in-flight registers to scratch).
    auto s2a = [&](int d, int t){
        int bb = bid >> 4, sq0 = (bid & 15)*8;
        float* s_sh  = smem;
        float* wa_sh = smem + 768;
        if (tid < 192){
            f32x4 acc;
            if (d == 0){
                f32x4 vc[6];
                #pragma unroll
                for (int cp = 0; cp < 6; cp++)
                    vc[cp] = ld4c(p.sP + (size_t)cp*12288 + bb*768 + tid*4);
                vm0();
                acc = *(const f32x4*)(p.b_att + tid*4);
                acc += *(const f32x4*)(p.pWp0 + ((size_t)bb*128 + t)*768 + tid*4);
                #pragma unroll
                for (int cp = 0; cp < 6; cp++){ vc[cp] = ldr4(vc[cp]); acc += vc[cp]; }
            } else {
                f32x4 vc[12];
                #pragma unroll
                for (int cp = 0; cp < 12; cp++)
                    vc[cp] = ld4c(p.sP + (size_t)cp*12288 + bb*768 + tid*4);
                vm0();
                acc = *(const f32x4*)(p.b_att + 768 + tid*4);
                #pragma unroll
                for (int cp = 0; cp < 12; cp++){ vc[cp] = ldr4(vc[cp]); acc += vc[cp]; }
            }
            *(f32x4*)&s_sh[tid*4] = acc;
        } else {
            int i0 = tid - 192;
            for (int rr = 0; rr < 3; rr++){
                int i = i0 + rr*64;
                *(f32x4*)&wa_sh[i*4] = *(const f32x4*)(p.w_att + d*768 + i*4);
            }
        }
        __syncthreads();
        int sq = sq0 + (tid >> 5), l = tid & 31;
        const float* qrow = p.qWq + ((size_t)(d*2048 + bb*128 + sq))*768;
        float part = 0.f;
        #pragma unroll
        for (int i = 0; i < 6; i++){
            int a = i*128 + l*4;
            f32x4 q  = *(const f32x4*)(qrow + a);
            f32x4 s4 = *(const f32x4*)(s_sh + a);
            f32x4 w4 = *(const f32x4*)(wa_sh + a);
            part += ftanh(q.x + s4.x)*w4.x + ftanh(q.y + s4.y)*w4.y
                  + ftanh(q.z + s4.z)*w4.z + ftanh(q.w + s4.w)*w4.w;
        }
        #pragma unroll
        for (int off = 16; off; off >>= 1) part += __shfl_xor(part, off, 32);
        if (l == 0){
            float e = (p.mask_q[bb*128 + sq] > 0.f) ? __expf(part) : 0.f;
            st1a(p.escore + bb*128 + sq, e);
        }
        __syncthreads();
    };

    // S2b weighted: 64 blocks, 4 per batch, 192 cols each
    auto s2b = [&](){
        int bb = bid >> 2, cg = bid & 3;
        float* e_sh = smem;    // 129
        if (tid < 128) e_sh[tid] = ld1a(p.escore + bb*128 + tid);
        __syncthreads();
        if (tid < 64){
            float v = e_sh[tid] + e_sh[tid + 64];
            #pragma unroll
            for (int off = 32; off; off >>= 1) v += __shfl_xor(v, off);
            if (tid == 0) e_sh[128] = 1.0f / v;
        }
        __syncthreads();
        float inv = e_sh[128];
        if (tid < 192){
            int cc = cg*192 + tid;
            const float* ip = p.iqT + ((size_t)bb*768 + cc)*128;
            float acc = 0.f;
            #pragma unroll 8
            for (int j = 0; j < 32; j++){
                f32x4 q  = *(const f32x4*)(ip + j*4);
                f32x4 e4 = *(const f32x4*)&e_sh[j*4];
                acc += dot4(q, e4);
            }
            st1a(p.wghtd + bb*768 + cc, acc*inv);
        }
        __syncthreads();
    };

    // reduce 6 copies of [16][3072] -> dst ; 48 blocks from boff (static unroll)
    auto red6 = [&](const float* src, float* dst, int boff){
        int gid = (bid - boff)*NTHR + tid;   // < 12288 f4
        f32x4 v[6];
        #pragma unroll
        for (int cp = 0; cp < 6; cp++)
            v[cp] = ld4c(src + (size_t)cp*49152 + gid*4);
        vm0();
        f32x4 a = {0,0,0,0};
        #pragma unroll
        for (int cp = 0; cp < 6; cp++){ v[cp] = ldr4(v[cp]); a += v[cp]; }
        st4c(dst + gid*4, a);
    };

    // gates: 16 blocks
    auto gates = [&](int d, int t){
        int bb = bid;
        float* wi_sh = smem;
        float* wh_sh = smem + 3072;
        float* c_sh  = smem + 6144;
        float* red   = smem + 6928;
        const float mmv = p.mask_p[bb*128 + t];
        const float* gi = p.ln_i_g + d*3072; const float* bi = p.ln_i_b + d*3072;
        const float* gh = p.ln_h_g + d*3072; const float* bh = p.ln_h_b + d*3072;
        const float* gc = p.ln_c_g + d*768;  const float* bc = p.ln_c_b + d*768;
        const float* bias_d = p.bias + d*3072;

        float swi=0,qwi=0,swh=0,qwh=0;
        #pragma unroll
        for (int rep = 0; rep < 3; rep++){
            int j4 = tid + rep*256;
            int base = bb*3072 + j4*4;
            f32x4 v[6], wv, cv;
            #pragma unroll
            for (int cp = 0; cp < 6; cp++)
                v[cp] = ld4c(p.wiP + (size_t)cp*49152 + base);
            wv = ld4c(p.whR + base);
            if (d == 1) cv = ld4c(p.cwR + base);
            vm0();
            f32x4 a = {0,0,0,0};
            #pragma unroll
            for (int cp = 0; cp < 6; cp++){ v[cp] = ldr4(v[cp]); a += v[cp]; }
            if (d == 0){
                a += *(const f32x4*)(p.pWih0 + ((size_t)bb*128 + t)*3072 + j4*4);
            } else {
                cv = ldr4(cv); a += cv;
            }
            wv = ldr4(wv);
            *(f32x4*)&wi_sh[j4*4] = a;
            *(f32x4*)&wh_sh[j4*4] = wv;
            swi += a.x+a.y+a.z+a.w;   qwi += dot4(a,a);
            swh += wv.x+wv.y+wv.z+wv.w; qwh += dot4(wv,wv);
        }
        swi = bsum4(swi, red, tid);
        qwi = bsum4(qwi, red, tid);
        swh = bsum4(swh, red, tid);
        qwh = bsum4(qwh, red, tid);
        float mi = swi/3072.f, vi = fmaxf((qwi - 3072.f*mi*mi)/3071.f, 0.f);
        float mh = swh/3072.f, vh = fmaxf((qwh - 3072.f*mh*mh)/3071.f, 0.f);
        float ivi = 1.f/(sqrtf(vi + 1e-6f) + 1e-6f);
        float ivh = 1.f/(sqrtf(vh + 1e-6f) + 1e-6f);

        for (int j = tid; j < 3072; j += NTHR){
            float pre = mmv*(gi[j]*(wi_sh[j]-mi)*ivi + bi[j])
                      + mmv*(gh[j]*(wh_sh[j]-mh)*ivh + bh[j])
                      + bias_d[j];
            wi_sh[j] = pre;
        }
        __syncthreads();

        float sc=0,qc=0;
        for (int idx = tid; idx < 384; idx += NTHR){
            int u = idx*2;
            float2 c_old = ld2a(p.c + (size_t)d*12288 + bb*768 + u);
            float f0  = wi_sh[u],        f1  = wi_sh[u+1];
            float i0  = wi_sh[768+u],    i1  = wi_sh[768+u+1];
            float g0  = wi_sh[2304+u],   g1  = wi_sh[2304+u+1];
            float c10 = fsigmoid(f0)*c_old.x + fsigmoid(i0)*ftanh(g0);
            float c11 = fsigmoid(f1)*c_old.y + fsigmoid(i1)*ftanh(g1);
            c10 = c10*mmv + c_old.x*(1.f - mmv);
            c11 = c11*mmv + c_old.y*(1.f - mmv);
            st2a(p.c + (size_t)d*12288 + bb*768 + u, c10, c11);
            c_sh[u] = c10; c_sh[u+1] = c11;
            sc += c10 + c11; qc += c10*c10 + c11*c11;
        }
        sc = bsum4(sc, red, tid);
        qc = bsum4(qc, red, tid);
        float mc = sc/768.f, vc = fmaxf((qc - 768.f*mc*mc)/767.f, 0.f);
        float ivc = 1.f/(sqrtf(vc + 1e-6f) + 1e-6f);

        for (int idx = tid; idx < 384; idx += NTHR){
            int u = idx*2;
            float2 h_old = ld2a(p.h + (size_t)d*12288 + bb*768 + u);
            float o0 = wi_sh[1536+u], o1 = wi_sh[1536+u+1];
            float l0 = (gc[u]*(c_sh[u]-mc)*ivc + bc[u])*mmv;
            float l1 = (gc[u+1]*(c_sh[u+1]-mc)*ivc + bc[u+1])*mmv;
            float h10 = fsigmoid(o0)*ftanh(l0);
            float h11 = fsigmoid(o1)*ftanh(l1);
            h10 = h10*mmv + h_old.x*(1.f - mmv);
            h11 = h11*mmv + h_old.y*(1.f - mmv);
            st2a(p.h + (size_t)d*12288 + bb*768 + u, h10, h11);
            if (d == 1){
                float2 ov = { h10, h11 };
                *(float2*)(p.out + ((size_t)bb*128 + t)*768 + u) = ov;
            }
        }
        __syncthreads();
    };

    // ---- prologue: zero h,c (12288 f4); write mask tail ----
    {
        int gid = bid*NTHR + tid;
        f32x4 z = {0,0,0,0};
        if (gid < 12288) st4c(p.h + (size_t)gid*4, z);
        if (gid < 2048)  p.out[(size_t)16*128*768 + gid] = p.mask_p[gid];
    }
    gsync(p.bar, bid, n); n++;

    for (int t = 0; t < 128; ++t){
        for (int d = 0; d < 2; ++d){
            const float* h_d = p.h + (size_t)d*12288;

            // ===== S1: h/cur weight matmuls (64-col tiles x 6 kc) =====
            {
                int ntile = (d == 0) ? 60 : 120;
                if (bid < ntile*6){
                    int tile = bid / 6, kc = bid % 6, k0 = kc*128;
                    if (d == 0){
                        stage128(h_d, k0);
                        if (tile < 12)
                            mm128(p.Wr, 768, p.sP + (size_t)kc*12288, tile*64, k0);
                        else
                            mm128(p.W_hh, 3072, p.whP + (size_t)kc*49152, (tile-12)*64, k0);
                    } else {
                        bool useCur = (tile >= 12 && tile < 24) || (tile >= 72);
                        stage128(useCur ? p.h : h_d, k0);
                        if (tile < 12)
                            mm128(p.Wr + (size_t)589824, 768,
                                  p.sP + (size_t)kc*12288, tile*64, k0);
                        else if (tile < 24)
                            mm128(p.Wp + (size_t)589824, 768,
                                  p.sP + (size_t)(6+kc)*12288, (tile-12)*64, k0);
                        else if (tile < 72)
                            mm128(p.W_hh + (size_t)2359296, 3072,
                                  p.whP + (size_t)kc*49152, (tile-24)*64, k0);
                        else
                            mm128(p.W_ih + (size_t)4718592, 3072,
                                  p.cwP + (size_t)kc*49152, (tile-72)*64, k0);
                    }
                }
            }
            gsync(p.bar, bid, n); n++;

            // ===== S2a: scores (256 blocks) =====
            if (bid < 256) s2a(d, t);
            gsync(p.bar, bid, n); n++;

            // ===== S2b: weighted (64) + wh/cw reduce (bid 64..160) =====
            if (bid < 64){
                s2b();
            } else if (bid < 112){
                red6(p.whP, p.whR, 64);
            } else if (bid < 160){
                if (d == 1) red6(p.cwP, p.cwR, 112);
            }
            gsync(p.bar, bid, n); n++;

            // ===== S3: wi matmul (48 tiles x 6 kc = 288 blocks) =====
            if (bid < 288){
                int tile = bid / 6, kc = bid % 6, k0 = kc*128;
                stage128(p.wghtd, k0);
                mm128(p.W_ih + (size_t)d*4718592 + (size_t)2359296, 3072,
                      p.wiP + (size_t)kc*49152, tile*64, k0);
            }
            gsync(p.bar, bid, n); n++;

            // ===== S4: LN + gates (16 blocks) =====
            if (bid < 16) gates(d, t);
            gsync(p.bar, bid, n); n++;
        }
    }
}

// ---------- precompute GEMM (f32 out; validated R0/R5/R7 kernel) ----------
__global__ __launch_bounds__(256) void k_mm_pre(
    const float* __restrict__ Ain, const float* __restrict__ W,
    float* __restrict__ C, int ldw, int ncols)
{
    __shared__ float Ash[16][772];
    int rowbase = blockIdx.y*16;
    for (int r = 0; r < 16; r++)
        for (int i = threadIdx.x; i < 768; i += 256)
            Ash[r][i] = Ain[(size_t)(rowbase + r)*768 + i];
    __syncthreads();
    int lane = threadIdx.x & 63;
    int colq = lane & 15, rsub = lane >> 4, wq = threadIdx.x >> 6;
    int r = wq*4 + rsub;
    int col = blockIdx.x*64 + colq*4;
    float4 acc = {0.f,0.f,0.f,0.f};
    const float* Wc = W + col;
    for (int k = 0; k < 768; k += 4){
        float4 a4 = *(const float4*)&Ash[r][k];
        float4 w0 = *(const float4*)(Wc + (size_t)(k+0)*ldw);
        float4 w1 = *(const float4*)(Wc + (size_t)(k+1)*ldw);
        float4 w2 = *(const float4*)(Wc + (size_t)(k+2)*ldw);
        float4 w3 = *(const float4*)(Wc + (size_t)(k+3)*ldw);
        acc.x += a4.x*w0.x + a4.y*w1.x + a4.z*w2.x + a4.w*w3.x;
        acc.y += a4.x*w0.y + a4.y*w1.y + a4.z*w2.y + a4.w*w3.y;
        acc.z += a4.x*w0.z + a4.y*w1.z + a4.z*w2.z + a4.w*w3.z;
        acc.w += a4.x*w0.w + a4.y*w1.w + a4.z*w2.w + a4.w*w3.w;
    }
    *(float4*)(C + (size_t)(rowbase + r)*ncols + col) = acc;
}

// ---------- transpose input_q -> iqT[b][c][sq] f32 ----------
__global__ __launch_bounds__(256) void k_transq(
    const float* __restrict__ iq, float* __restrict__ iqT)
{
    __shared__ float Tsh[32][136];
    int c0 = blockIdx.x*32, b = blockIdx.y;
    for (int rep = 0; rep < 4; rep++){
        int idx = threadIdx.x + rep*256;
        int sq = idx >> 3, cq = idx & 7;
        float4 v = *(const float4*)(iq + ((size_t)b*128 + sq)*768 + c0 + cq*4);
        Tsh[cq*4+0][sq] = v.x;
        Tsh[cq*4+1][sq] = v.y;
        Tsh[cq*4+2][sq] = v.z;
        Tsh[cq*4+3][sq] = v.w;
    }
    __syncthreads();
    for (int rep = 0; rep < 4; rep++){
        int idx = threadIdx.x + rep*256;
        int cl = idx >> 5, sq4 = (idx & 31)*4;
        float4 v = *(const float4*)&Tsh[cl][sq4];
        *(float4*)(iqT + ((size_t)b*768 + c0 + cl)*128 + sq4) = v;
    }
}

extern "C" void kernel_launch(void* const* d_in, const int* in_sizes, int n_in,
                              void* d_out, int out_size, void* d_ws, size_t ws_size,
                              hipStream_t stream)
{
    (void)in_sizes; (void)n_in; (void)out_size; (void)ws_size;
    Params P;
    P.input_p = (const float*)d_in[0];
    P.mask_p  = (const float*)d_in[1];
    P.input_q = (const float*)d_in[2];
    P.mask_q  = (const float*)d_in[3];
    P.W_ih    = (const float*)d_in[4];
    P.W_hh    = (const float*)d_in[5];
    P.bias    = (const float*)d_in[6];
    P.ln_i_g  = (const float*)d_in[7];
    P.ln_i_b  = (const float*)d_in[8];
    P.ln_h_g  = (const float*)d_in[9];
    P.ln_h_b  = (const float*)d_in[10];
    P.ln_c_g  = (const float*)d_in[11];
    P.ln_c_b  = (const float*)d_in[12];
    P.Wq      = (const float*)d_in[13];
    P.Wp      = (const float*)d_in[14];
    P.Wr      = (const float*)d_in[15];
    P.w_att   = (const float*)d_in[16];
    P.b_att   = (const float*)d_in[17];
    P.out     = (float*)d_out;

    float* ws = (float*)d_ws;
    size_t off = 0;
    auto alloc = [&](size_t nfloat)->float*{
        float* r = ws + off;
        off += (nfloat + 63) & ~(size_t)63;
        return r;
    };
    P.qWq    = alloc((size_t)2*2048*768);
    P.iqT    = alloc((size_t)16*768*128);
    P.pWp0   = alloc((size_t)2048*768);
    P.pWih0  = alloc((size_t)2048*3072);
    P.h      = alloc(24576);
    P.c      = alloc(24576);          // contiguous after h
    P.sP     = alloc((size_t)12*12288);
    P.whP    = alloc((size_t)6*49152);
    P.cwP    = alloc((size_t)6*49152);
    P.wiP    = alloc((size_t)6*49152);
    P.whR    = alloc(49152);
    P.cwR    = alloc(49152);
    P.wghtd  = alloc(12288);
    P.escore = alloc(2048);
    P.bar    = (unsigned*)alloc(2048);

    (void)hipMemsetAsync((void*)P.bar, 0, 2048*sizeof(unsigned), stream);
    k_mm_pre<<<dim3(12,128), 256, 0, stream>>>(P.input_q, P.Wq, P.qWq, 768, 768);
    k_mm_pre<<<dim3(12,128), 256, 0, stream>>>(P.input_q, P.Wq + (size_t)589824,
                                               P.qWq + (size_t)2048*768, 768, 768);
    k_mm_pre<<<dim3(12,128), 256, 0, stream>>>(P.input_p, P.Wp, P.pWp0, 768, 768);
    k_mm_pre<<<dim3(48,128), 256, 0, stream>>>(P.input_p, P.W_ih, P.pWih0, 3072, 3072);
    k_transq<<<dim3(24,16), 256, 0, stream>>>(P.input_q, P.iqT);
    coop_kernel<<<dim3(NBLK), dim3(NTHR), 0, stream>>>(P);
}